// Round 10
// baseline (163.144 us; speedup 1.0000x reference)
//
#include <hip/hip_runtime.h>

#define NSEQ 2048
#define NB 2
#define NH 8
#define HD 64
#define DMODEL 1024
#define DINNER 512   // NH*HD

// partial slot for k-split strips: O[16][64] f32 + m[16] + l[16] = 1056 floats
#define SLOT_F 1056
#define LOG2E 1.44269504f

typedef __attribute__((ext_vector_type(8))) short bf16x8;
typedef __attribute__((ext_vector_type(4))) float f32x4;

__device__ __forceinline__ ushort f2bf(float f) {
  uint u = __float_as_uint(f);
  uint r = (u + 0x7fffu + ((u >> 16) & 1u)) >> 16;
  return (ushort)r;
}

// slot offset within a bh for strip s (>=32), chunk c
__device__ __forceinline__ int soff(int s, int c) {
  if (s < 64) return (s - 32) * 2 + c;
  if (s < 96) return 64 + (s - 64) * 3 + c;
  return 160 + (s - 96) * 4 + c;
}

// ---------------- prep 1: cast x (4096x1024 fp32) -> bf16 ----------------
__global__ __launch_bounds__(256) void cast_x_kernel(
    const float* __restrict__ x, ushort* __restrict__ xb) {
  size_t i = ((size_t)blockIdx.x * 256 + threadIdx.x) * 8;
  float4 a = *(const float4*)(x + i);
  float4 b = *(const float4*)(x + i + 4);
  ushort4 o1, o2;
  o1.x = f2bf(a.x); o1.y = f2bf(a.y); o1.z = f2bf(a.z); o1.w = f2bf(a.w);
  o2.x = f2bf(b.x); o2.y = f2bf(b.y); o2.z = f2bf(b.z); o2.w = f2bf(b.w);
  *(ushort4*)(xb + i) = o1;
  *(ushort4*)(xb + i + 4) = o2;
}

// ---------------- prep 2: transpose+cast weights to B^T[n][k] bf16 --------
__global__ __launch_bounds__(256) void transpose_cast_kernel(
    const float* __restrict__ srcA, const float* __restrict__ srcB,
    int ldA, int ldB, int nsplit, int Ktot, ushort* __restrict__ dst) {
  __shared__ float t[64][65];
  const int k0 = blockIdx.x * 64;
  const int n0 = blockIdx.y * 64;
  const float* src; int ld, nb;
  if (n0 < nsplit) { src = srcA; ld = ldA; nb = n0; }
  else { src = srcB; ld = ldB; nb = n0 - nsplit; }
  const int r = threadIdx.x >> 4;
  const int c = (threadIdx.x & 15) * 4;
#pragma unroll
  for (int rr = r; rr < 64; rr += 16) {
    float4 v = *(const float4*)(src + (size_t)(k0 + rr) * ld + nb + c);
    t[rr][c + 0] = v.x; t[rr][c + 1] = v.y; t[rr][c + 2] = v.z; t[rr][c + 3] = v.w;
  }
  __syncthreads();
#pragma unroll
  for (int rr = r; rr < 64; rr += 16) {
    ushort4 o;
    o.x = f2bf(t[c + 0][rr]); o.y = f2bf(t[c + 1][rr]);
    o.z = f2bf(t[c + 2][rr]); o.w = f2bf(t[c + 3][rr]);
    *(ushort4*)(dst + (size_t)(n0 + rr) * Ktot + k0 + c) = o;
  }
}

// ---------------- shared MFMA GEMM tile machinery ----------------
__device__ __forceinline__ void stage_tile(const ushort* __restrict__ src, int ld,
                                           int row0, int k0, ushort* lds, int tid) {
#pragma unroll
  for (int i = 0; i < 4; ++i) {
    const int cix = i * 256 + tid;
    const int row = cix >> 3, j = cix & 7;
    uint4 v = *(const uint4*)(src + (size_t)(row0 + row) * ld + k0 + j * 8);
    *(uint4*)((char*)lds + row * 128 + ((j ^ (row & 7)) << 4)) = v;
  }
}

// 128x128 tile, BK=64, 4 waves (2x2), each wave 64x64 = 4x4 16x16 frags.
__device__ __forceinline__ void gemm_tile(const ushort* __restrict__ A,
                                          const ushort* __restrict__ Bt, int K,
                                          int m0, int n0, ushort* As, ushort* Bs,
                                          int tid, f32x4 acc[4][4]) {
  const int lane = tid & 63;
  const int w = tid >> 6;
  const int wr = w >> 1, wc = w & 1;
  const int lr = lane & 15, lg = lane >> 4;
  for (int k0 = 0; k0 < K; k0 += 64) {
    __syncthreads();
    stage_tile(A, K, m0, k0, As, tid);
    stage_tile(Bt, K, n0, k0, Bs, tid);
    __syncthreads();
#pragma unroll
    for (int kk = 0; kk < 2; ++kk) {
      bf16x8 af[4], bfr[4];
#pragma unroll
      for (int mi = 0; mi < 4; ++mi) {
        const int r = wr * 64 + mi * 16 + lr;
        af[mi] = *(const bf16x8*)((char*)As + r * 128 + (((kk * 4 + lg) ^ (r & 7)) << 4));
      }
#pragma unroll
      for (int ni = 0; ni < 4; ++ni) {
        const int r = wc * 64 + ni * 16 + lr;
        bfr[ni] = *(const bf16x8*)((char*)Bs + r * 128 + (((kk * 4 + lg) ^ (r & 7)) << 4));
      }
#pragma unroll
      for (int mi = 0; mi < 4; ++mi)
#pragma unroll
        for (int ni = 0; ni < 4; ++ni)
          acc[mi][ni] = __builtin_amdgcn_mfma_f32_16x16x32_bf16(af[mi], bfr[ni],
                                                                acc[mi][ni], 0, 0, 0);
    }
  }
}

// ---------------- Kernel: QKV GEMM (bf16 MFMA) ----------------
// q -> [b*h][n][d] scaled by SCALE*log2e; k -> [b][key][d]; v -> [b][d][key]
__global__ __launch_bounds__(256) void qkv_mfma_kernel(
    const ushort* __restrict__ xb, const ushort* __restrict__ WT1,
    ushort* __restrict__ qb, ushort* __restrict__ kb, ushort* __restrict__ vt) {
  __shared__ ushort As[128 * 64];
  __shared__ ushort Bs[128 * 64];
  const int tid = threadIdx.x;
  const int m0 = blockIdx.x * 128, n0 = blockIdx.y * 128;
  f32x4 acc[4][4];
#pragma unroll
  for (int a = 0; a < 4; ++a)
#pragma unroll
    for (int b = 0; b < 4; ++b) acc[a][b] = (f32x4){0.f, 0.f, 0.f, 0.f};
  gemm_tile(xb, WT1, DMODEL, m0, n0, As, Bs, tid, acc);
  const int lane = tid & 63;
  const int w = tid >> 6;
  const int wr = w >> 1, wc = w & 1;
  const int lr = lane & 15, lg = lane >> 4;
#pragma unroll
  for (int mi = 0; mi < 4; ++mi)
#pragma unroll
    for (int ni = 0; ni < 4; ++ni) {
      const int n = n0 + wc * 64 + ni * 16 + lr;
      if (n >= 640) continue;
#pragma unroll
      for (int r = 0; r < 4; ++r) {
        const int m = m0 + wr * 64 + mi * 16 + lg * 4 + r;
        const int bb = m >> 11, key = m & (NSEQ - 1);
        const float v = acc[mi][ni][r];
        if (n < DINNER) {
          const int h = n >> 6, d = n & 63;
          qb[((size_t)((bb * NH + h) * NSEQ) + key) * HD + d] =
              f2bf(v * (0.125f * LOG2E));
        } else if (n < DINNER + HD) {
          kb[((size_t)(bb * NSEQ) + key) * HD + (n - DINNER)] = f2bf(v);
        } else {
          vt[((size_t)(bb * HD) + (n - DINNER - HD)) * NSEQ + key] = f2bf(v);
        }
      }
    }
}

// ---------------- Kernel: out GEMM (bf16 MFMA) + bias, fp32 out ------------
__global__ __launch_bounds__(256) void out_mfma_kernel(
    const ushort* __restrict__ ab, const ushort* __restrict__ WoT,
    const float* __restrict__ bo, float* __restrict__ out) {
  __shared__ ushort As[128 * 64];
  __shared__ ushort Bs[128 * 64];
  const int tid = threadIdx.x;
  const int m0 = blockIdx.x * 128, n0 = blockIdx.y * 128;
  f32x4 acc[4][4];
#pragma unroll
  for (int a = 0; a < 4; ++a)
#pragma unroll
    for (int b = 0; b < 4; ++b) acc[a][b] = (f32x4){0.f, 0.f, 0.f, 0.f};
  gemm_tile(ab, WoT, DINNER, m0, n0, As, Bs, tid, acc);
  const int lane = tid & 63;
  const int w = tid >> 6;
  const int wr = w >> 1, wc = w & 1;
  const int lr = lane & 15, lg = lane >> 4;
#pragma unroll
  for (int mi = 0; mi < 4; ++mi)
#pragma unroll
    for (int ni = 0; ni < 4; ++ni) {
      const int n = n0 + wc * 64 + ni * 16 + lr;
      const float bias = bo[n];
#pragma unroll
      for (int r = 0; r < 4; ++r) {
        const int m = m0 + wr * 64 + mi * 16 + lg * 4 + r;
        out[(size_t)m * DMODEL + n] = acc[mi][ni][r] + bias;
      }
    }
}

// ---------------- Kernel: causal flash attention, 1 wave / block -----------
// Barrier-free: K/V fragments loaded register-direct from global (L2-resident).
// Block = (bh, 16-row q-strip s, k-chunk c of <=4 pair-iters = 512 keys).
// Swapped MFMA: S^T = mfma(K, Q), O^T = mfma(V^T, P); lane owns q = lane&15.
// Grid 16 bh x 320 items; strips s>=32 produce partials, merged by next kernel.
__global__ __launch_bounds__(64, 3) void attn_mfma_kernel(
    const ushort* __restrict__ qb, const ushort* __restrict__ kb,
    const ushort* __restrict__ vt, const float* __restrict__ rpb,
    ushort* __restrict__ ob, float* __restrict__ scratch) {
  __shared__ ushort Ps[16 * 128];   // [q 16][key 128] swizzled, 4KB, wave-local
  const int lane = threadIdx.x;
  const int lr = lane & 15;
  const int lg = lane >> 4;
  const int id = blockIdx.x;
  const int bh = id & 15;
  const int t = 319 - (id >> 4);    // longest chunks first
  int s, c;
  if (t < 32)       { s = t;                      c = 0; }
  else if (t < 96)  { int u = t - 32;  s = 32 + (u >> 1); c = u & 1; }
  else if (t < 192) { int u = t - 96;  s = 64 + u / 3;    c = u % 3; }
  else              { int u = t - 192; s = 96 + (u >> 2); c = u & 3; }
  const int bb = bh >> 3, h = bh & 7;
  const int pdiag = s >> 3;               // pair containing the diagonal
  const int p0 = c * 4;
  const int p1 = min(p0 + 4, pdiag + 1);
  const int nch = (pdiag + 4) >> 2;       // ceil(npairs/4)
  const int qg = s * 16 + lr;             // this lane's q-row

  const ushort* kbase = kb + (size_t)bb * NSEQ * HD;
  const ushort* vbase = vt + (size_t)bb * HD * NSEQ;

  // Q fragments (row q=lr) in registers
  bf16x8 qf[2];
  {
    const ushort* qrow = qb + ((size_t)(bh * NSEQ) + qg) * HD + lg * 8;
    qf[0] = *(const bf16x8*)qrow;
    qf[1] = *(const bf16x8*)(qrow + 32);
  }
  f32x4 oaccT[4];   // O^T: row d = dt*16 + lg*4 + r, col q = lr
#pragma unroll
  for (int dt = 0; dt < 4; ++dt) oaccT[dt] = (f32x4){0.f, 0.f, 0.f, 0.f};
  float m_run = -1e30f, l_run = 0.f;

  for (int p = p0; p < p1; ++p) {
    const int key0 = p * 128;
    // ---- bias for this lane's q-row (8 x 16B, contiguous 512B window)
    f32x4 bias[8];
    {
      const float* br =
          rpb + (size_t)h * NSEQ * NSEQ + (size_t)qg * NSEQ + key0 + lg * 4;
#pragma unroll
      for (int ct = 0; ct < 8; ++ct) bias[ct] = *(const f32x4*)(br + ct * 16);
    }
    // ---- S^T = K Q^T : 16 MFMAs, K frags register-direct from global
    f32x4 sv[8];
    __builtin_amdgcn_s_setprio(1);
#pragma unroll
    for (int ct = 0; ct < 8; ++ct) {
      const ushort* krow =
          kbase + (size_t)(key0 + ct * 16 + lr) * HD + lg * 8;
      bf16x8 kf0 = *(const bf16x8*)krow;
      bf16x8 kf1 = *(const bf16x8*)(krow + 32);
      sv[ct] = (f32x4){0.f, 0.f, 0.f, 0.f};
      sv[ct] = __builtin_amdgcn_mfma_f32_16x16x32_bf16(kf0, qf[0], sv[ct], 0, 0, 0);
      sv[ct] = __builtin_amdgcn_mfma_f32_16x16x32_bf16(kf1, qf[1], sv[ct], 0, 0, 0);
    }
    __builtin_amdgcn_s_setprio(0);
    // ---- + bias*log2e, causal mask on the diagonal pair
#pragma unroll
    for (int ct = 0; ct < 8; ++ct)
#pragma unroll
      for (int r = 0; r < 4; ++r)
        sv[ct][r] = fmaf(bias[ct][r], LOG2E, sv[ct][r]);
    if (p == pdiag) {
#pragma unroll
      for (int ct = 0; ct < 8; ++ct) {
        const int kg = key0 + ct * 16 + lg * 4;
#pragma unroll
        for (int r = 0; r < 4; ++r)
          if (kg + r > qg) sv[ct][r] = -1e30f;
      }
    }
    // ---- online softmax, lane-local row; log2 domain
    float cm[8];
#pragma unroll
    for (int ct = 0; ct < 8; ++ct)
      cm[ct] = fmaxf(fmaxf(sv[ct][0], sv[ct][1]), fmaxf(sv[ct][2], sv[ct][3]));
    float mt = fmaxf(fmaxf(fmaxf(cm[0], cm[1]), fmaxf(cm[2], cm[3])),
                     fmaxf(fmaxf(cm[4], cm[5]), fmaxf(cm[6], cm[7])));
    mt = fmaxf(mt, __shfl_xor(mt, 16, 64));
    mt = fmaxf(mt, __shfl_xor(mt, 32, 64));
    const float m_new = fmaxf(m_run, mt);
    const float fac = exp2f(m_run - m_new);
    m_run = m_new;
    float cs[8];
#pragma unroll
    for (int ct = 0; ct < 8; ++ct) {
#pragma unroll
      for (int r = 0; r < 4; ++r) sv[ct][r] = exp2f(sv[ct][r] - m_new);
      cs[ct] = (sv[ct][0] + sv[ct][1]) + (sv[ct][2] + sv[ct][3]);
    }
    float ls = ((cs[0] + cs[1]) + (cs[2] + cs[3])) +
               ((cs[4] + cs[5]) + (cs[6] + cs[7]));
    ls += __shfl_xor(ls, 16, 64);
    ls += __shfl_xor(ls, 32, 64);
    l_run = l_run * fac + ls;
#pragma unroll
    for (int dt = 0; dt < 4; ++dt) oaccT[dt] *= fac;
    // ---- P -> wave-local LDS [q][key] (swizzled); no barrier needed
    char* Pw = (char*)Ps;
#pragma unroll
    for (int ct = 0; ct < 8; ++ct) {
      uint u01, u23;
      asm("v_cvt_pk_bf16_f32 %0, %1, %2" : "=v"(u01) : "v"(sv[ct][0]), "v"(sv[ct][1]));
      asm("v_cvt_pk_bf16_f32 %0, %1, %2" : "=v"(u23) : "v"(sv[ct][2]), "v"(sv[ct][3]));
      const int chunk = 2 * ct + (lg >> 1);
      uint2 uv; uv.x = u01; uv.y = u23;
      *(uint2*)(Pw + lr * 256 + (((chunk ^ lr) << 4) | ((lg & 1) * 8))) = uv;
    }
    // ---- O^T += V^T P : 16 MFMAs, V frags register-direct from global
    __builtin_amdgcn_s_setprio(1);
#pragma unroll
    for (int kk = 0; kk < 4; ++kk) {
      bf16x8 pf = *(const bf16x8*)(Pw + lr * 256 + (((kk * 4 + lg) ^ lr) << 4));
#pragma unroll
      for (int dt = 0; dt < 4; ++dt) {
        const ushort* vrow =
            vbase + (size_t)(dt * 16 + lr) * NSEQ + key0 + kk * 32 + lg * 8;
        bf16x8 vf = *(const bf16x8*)vrow;
        oaccT[dt] =
            __builtin_amdgcn_mfma_f32_16x16x32_bf16(vf, pf, oaccT[dt], 0, 0, 0);
      }
    }
    __builtin_amdgcn_s_setprio(0);
  }
  if (nch == 1) {
    // ---- direct epilogue: lane q = lr, d = dt*16 + lg*4 (+0..3)
    const float inv = 1.0f / l_run;
    ushort* dst = ob + ((size_t)(bb * NSEQ) + qg) * DINNER + h * HD;
#pragma unroll
    for (int dt = 0; dt < 4; ++dt) {
      uint u01, u23;
      const float o0 = oaccT[dt][0] * inv, o1 = oaccT[dt][1] * inv;
      const float o2 = oaccT[dt][2] * inv, o3 = oaccT[dt][3] * inv;
      asm("v_cvt_pk_bf16_f32 %0, %1, %2" : "=v"(u01) : "v"(o0), "v"(o1));
      asm("v_cvt_pk_bf16_f32 %0, %1, %2" : "=v"(u23) : "v"(o2), "v"(o3));
      uint2 uv; uv.x = u01; uv.y = u23;
      *(uint2*)(dst + dt * 16 + lg * 4) = uv;
    }
  } else {
    // ---- partial: slot [q 16][d 64] + m[16] + l[16]
    float* slot = scratch + ((size_t)(bh * 288) + soff(s, c)) * SLOT_F;
#pragma unroll
    for (int dt = 0; dt < 4; ++dt)
      *(f32x4*)(slot + lr * 64 + dt * 16 + lg * 4) = oaccT[dt];
    if (lg == 0) {
      slot[1024 + lr] = m_run;   // log2-domain max
      slot[1040 + lr] = l_run;
    }
  }
}

// ---------------- Kernel: merge partial strips (s >= 32, 2..4 chunks) ------
__global__ __launch_bounds__(64) void attn_merge_kernel(
    const float* __restrict__ scratch, ushort* __restrict__ ob) {
  const int bid = blockIdx.x;           // 16 bh x 96 strips
  const int bh = bid / 96;
  const int s = 32 + bid % 96;
  const int nch = ((s >> 3) + 4) >> 2;  // 2..4
  const int bb = bh >> 3, h = bh & 7;
  const float* base = scratch + ((size_t)(bh * 288) + soff(s, 0)) * SLOT_F;
  const int t = threadIdx.x;
  const int r = t >> 2;                 // q-row 0..15
  const int c0 = (t & 3) * 16;          // 16 d's
  float ms[4], M = -1e30f;
  for (int ch = 0; ch < nch; ++ch) {
    ms[ch] = base[(size_t)ch * SLOT_F + 1024 + r];
    M = fmaxf(M, ms[ch]);
  }
  float L = 0.f, sc[4];
  for (int ch = 0; ch < nch; ++ch) {
    sc[ch] = exp2f(ms[ch] - M);
    L += base[(size_t)ch * SLOT_F + 1040 + r] * sc[ch];
  }
  const float inv = 1.0f / L;
  float o[16];
#pragma unroll
  for (int j = 0; j < 16; ++j) o[j] = 0.f;
  for (int ch = 0; ch < nch; ++ch) {
    const float* orow = base + (size_t)ch * SLOT_F + r * 64 + c0;
    const float f = sc[ch];
#pragma unroll
    for (int j4 = 0; j4 < 4; ++j4) {
      float4 v = *(const float4*)(orow + j4 * 4);
      o[j4 * 4 + 0] += f * v.x;
      o[j4 * 4 + 1] += f * v.y;
      o[j4 * 4 + 2] += f * v.z;
      o[j4 * 4 + 3] += f * v.w;
    }
  }
  ushort* dst =
      ob + ((size_t)(bb * NSEQ) + s * 16 + r) * DINNER + h * HD + c0;
#pragma unroll
  for (int j = 0; j < 16; ++j) dst[j] = f2bf(o[j] * inv);
}

extern "C" void kernel_launch(void* const* d_in, const int* in_sizes, int n_in,
                              void* d_out, int out_size, void* d_ws, size_t ws_size,
                              hipStream_t stream) {
  (void)in_sizes; (void)n_in; (void)out_size; (void)ws_size;
  const float* x = (const float*)d_in[0];
  const float* rpb = (const float*)d_in[1];
  const float* Wq = (const float*)d_in[2];
  const float* Wkv = (const float*)d_in[3];
  const float* Wo = (const float*)d_in[4];
  const float* bo = (const float*)d_in[5];
  float* out = (float*)d_out;

  ushort* qbb = (ushort*)d_ws;                           // 16*2048*64
  ushort* kbb = qbb + (size_t)NB * NH * NSEQ * HD;       // 2*2048*64
  ushort* vtb = kbb + (size_t)NB * NSEQ * HD;            // 2*64*2048
  ushort* obuf = vtb + (size_t)NB * NSEQ * HD;           // 4096*512 bf16
  ushort* xb = obuf + (size_t)NB * NSEQ * DINNER;        // 4096*1024 bf16
  ushort* WT1 = xb + (size_t)NB * NSEQ * DMODEL;         // 640*1024 bf16
  ushort* WoT = WT1 + (size_t)640 * DMODEL;              // 1024*512 bf16
  float* scratch = (float*)(WoT + (size_t)DMODEL * DINNER);  // 16*288*1056 f32

  cast_x_kernel<<<dim3(2048), 256, 0, stream>>>(x, xb);
  transpose_cast_kernel<<<dim3(16, 10), 256, 0, stream>>>(Wq, Wkv, 512, 128, 512,
                                                          DMODEL, WT1);
  transpose_cast_kernel<<<dim3(8, 16), 256, 0, stream>>>(Wo, Wo, DMODEL, DMODEL,
                                                         DMODEL, DINNER, WoT);
  qkv_mfma_kernel<<<dim3(32, 5), 256, 0, stream>>>(xb, WT1, qbb, kbb, vtb);
  attn_mfma_kernel<<<dim3(16 * 320), 64, 0, stream>>>(qbb, kbb, vtb, rpb, obuf,
                                                      scratch);
  attn_merge_kernel<<<dim3(16 * 96), 64, 0, stream>>>(scratch, obuf);
  out_mfma_kernel<<<dim3(32, 8), 256, 0, stream>>>(obuf, WoT, bo, out);
}

// Round 11
// 100.407 us; speedup vs baseline: 1.6248x; 1.6248x over previous
//
#include <hip/hip_runtime.h>

#define NSEQ 2048
#define NB 2
#define NH 8
#define HD 64
#define DMODEL 1024
#define DINNER 512   // NH*HD

// partial slot: O[64][64] f32 + m[64] + l[64]
#define SLOT_F 4224
#define SLOTS_PER_BH 72
#define LOG2E 1.44269504f

typedef __attribute__((ext_vector_type(8))) short bf16x8;
typedef __attribute__((ext_vector_type(4))) float f32x4;

__device__ __forceinline__ ushort f2bf(float f) {
  uint u = __float_as_uint(f);
  uint r = (u + 0x7fffu + ((u >> 16) & 1u)) >> 16;
  return (ushort)r;
}

__device__ __forceinline__ int slot_off(int qt) {
  if (qt < 16) return (qt - 8) * 2;
  if (qt < 24) return 16 + (qt - 16) * 3;
  return 40 + (qt - 24) * 4;
}

// async global->LDS, 16B/lane; LDS dest wave-uniform base (+lane*16 by HW)
__device__ __forceinline__ void gld16(const ushort* g, ushort* l) {
  __builtin_amdgcn_global_load_lds(
      (const __attribute__((address_space(1))) uint*)g,
      (__attribute__((address_space(3))) uint*)l, 16, 0, 0);
}

// ---------------- prep 1: cast x (4096x1024 fp32) -> bf16 ----------------
__global__ __launch_bounds__(256) void cast_x_kernel(
    const float* __restrict__ x, ushort* __restrict__ xb) {
  size_t i = ((size_t)blockIdx.x * 256 + threadIdx.x) * 8;
  float4 a = *(const float4*)(x + i);
  float4 b = *(const float4*)(x + i + 4);
  ushort4 o1, o2;
  o1.x = f2bf(a.x); o1.y = f2bf(a.y); o1.z = f2bf(a.z); o1.w = f2bf(a.w);
  o2.x = f2bf(b.x); o2.y = f2bf(b.y); o2.z = f2bf(b.z); o2.w = f2bf(b.w);
  *(ushort4*)(xb + i) = o1;
  *(ushort4*)(xb + i + 4) = o2;
}

// ---------------- prep 2: transpose+cast weights to B^T[n][k] bf16 --------
__global__ __launch_bounds__(256) void transpose_cast_kernel(
    const float* __restrict__ srcA, const float* __restrict__ srcB,
    int ldA, int ldB, int nsplit, int Ktot, ushort* __restrict__ dst) {
  __shared__ float t[64][65];
  const int k0 = blockIdx.x * 64;
  const int n0 = blockIdx.y * 64;
  const float* src; int ld, nb;
  if (n0 < nsplit) { src = srcA; ld = ldA; nb = n0; }
  else { src = srcB; ld = ldB; nb = n0 - nsplit; }
  const int r = threadIdx.x >> 4;
  const int c = (threadIdx.x & 15) * 4;
#pragma unroll
  for (int rr = r; rr < 64; rr += 16) {
    float4 v = *(const float4*)(src + (size_t)(k0 + rr) * ld + nb + c);
    t[rr][c + 0] = v.x; t[rr][c + 1] = v.y; t[rr][c + 2] = v.z; t[rr][c + 3] = v.w;
  }
  __syncthreads();
#pragma unroll
  for (int rr = r; rr < 64; rr += 16) {
    ushort4 o;
    o.x = f2bf(t[c + 0][rr]); o.y = f2bf(t[c + 1][rr]);
    o.z = f2bf(t[c + 2][rr]); o.w = f2bf(t[c + 3][rr]);
    *(ushort4*)(dst + (size_t)(n0 + rr) * Ktot + k0 + c) = o;
  }
}

// ---------------- shared MFMA GEMM tile machinery ----------------
__device__ __forceinline__ void stage_tile(const ushort* __restrict__ src, int ld,
                                           int row0, int k0, ushort* lds, int tid) {
#pragma unroll
  for (int i = 0; i < 4; ++i) {
    const int cix = i * 256 + tid;
    const int row = cix >> 3, j = cix & 7;
    uint4 v = *(const uint4*)(src + (size_t)(row0 + row) * ld + k0 + j * 8);
    *(uint4*)((char*)lds + row * 128 + ((j ^ (row & 7)) << 4)) = v;
  }
}

// 128x128 tile, BK=64, 4 waves (2x2), each wave 64x64 = 4x4 16x16 frags.
__device__ __forceinline__ void gemm_tile(const ushort* __restrict__ A,
                                          const ushort* __restrict__ Bt, int K,
                                          int m0, int n0, ushort* As, ushort* Bs,
                                          int tid, f32x4 acc[4][4]) {
  const int lane = tid & 63;
  const int w = tid >> 6;
  const int wr = w >> 1, wc = w & 1;
  const int lr = lane & 15, lg = lane >> 4;
  for (int k0 = 0; k0 < K; k0 += 64) {
    __syncthreads();
    stage_tile(A, K, m0, k0, As, tid);
    stage_tile(Bt, K, n0, k0, Bs, tid);
    __syncthreads();
#pragma unroll
    for (int kk = 0; kk < 2; ++kk) {
      bf16x8 af[4], bfr[4];
#pragma unroll
      for (int mi = 0; mi < 4; ++mi) {
        const int r = wr * 64 + mi * 16 + lr;
        af[mi] = *(const bf16x8*)((char*)As + r * 128 + (((kk * 4 + lg) ^ (r & 7)) << 4));
      }
#pragma unroll
      for (int ni = 0; ni < 4; ++ni) {
        const int r = wc * 64 + ni * 16 + lr;
        bfr[ni] = *(const bf16x8*)((char*)Bs + r * 128 + (((kk * 4 + lg) ^ (r & 7)) << 4));
      }
#pragma unroll
      for (int mi = 0; mi < 4; ++mi)
#pragma unroll
        for (int ni = 0; ni < 4; ++ni)
          acc[mi][ni] = __builtin_amdgcn_mfma_f32_16x16x32_bf16(af[mi], bfr[ni],
                                                                acc[mi][ni], 0, 0, 0);
    }
  }
}

// ---------------- Kernel: QKV GEMM (bf16 MFMA) ----------------
// q -> [b*h][n][d] scaled by SCALE*log2e; k,v -> PRE-SWIZZLED 64-key LDS tiles.
__global__ __launch_bounds__(256) void qkv_mfma_kernel(
    const ushort* __restrict__ xb, const ushort* __restrict__ WT1,
    ushort* __restrict__ qb, ushort* __restrict__ ksw, ushort* __restrict__ vsw) {
  __shared__ ushort As[128 * 64];
  __shared__ ushort Bs[128 * 64];
  const int tid = threadIdx.x;
  const int m0 = blockIdx.x * 128, n0 = blockIdx.y * 128;
  f32x4 acc[4][4];
#pragma unroll
  for (int a = 0; a < 4; ++a)
#pragma unroll
    for (int b = 0; b < 4; ++b) acc[a][b] = (f32x4){0.f, 0.f, 0.f, 0.f};
  gemm_tile(xb, WT1, DMODEL, m0, n0, As, Bs, tid, acc);
  const int lane = tid & 63;
  const int w = tid >> 6;
  const int wr = w >> 1, wc = w & 1;
  const int lr = lane & 15, lg = lane >> 4;
#pragma unroll
  for (int mi = 0; mi < 4; ++mi)
#pragma unroll
    for (int ni = 0; ni < 4; ++ni) {
      const int n = n0 + wc * 64 + ni * 16 + lr;
      if (n >= 640) continue;
#pragma unroll
      for (int r = 0; r < 4; ++r) {
        const int m = m0 + wr * 64 + mi * 16 + lg * 4 + r;
        const int bb = m >> 11, key = m & (NSEQ - 1);
        const float v = acc[mi][ni][r];
        if (n < DINNER) {
          const int h = n >> 6, d = n & 63;
          qb[((size_t)((bb * NH + h) * NSEQ) + key) * HD + d] =
              f2bf(v * (0.125f * LOG2E));
        } else if (n < DINNER + HD) {
          // K tile t=key>>6, row=key&63: chunk(d>>3) ^ (row&7)
          const int d = n - DINNER;
          const int t = key >> 6, row = key & 63;
          ksw[(size_t)((bb * 32 + t) * 64 + row) * 64 +
              (((d >> 3) ^ (row & 7)) << 3) + (d & 7)] = f2bf(v);
        } else {
          // V^T tile t=key>>6, row=d: chunk(kk>>3) ^ (d&7)
          const int d = n - DINNER - HD;
          const int t = key >> 6, kk = key & 63;
          vsw[(size_t)((bb * 32 + t) * 64 + d) * 64 +
              (((kk >> 3) ^ (d & 7)) << 3) + (kk & 7)] = f2bf(v);
        }
      }
    }
}

// ---------------- Kernel: out GEMM (bf16 MFMA) + bias, fp32 out ------------
__global__ __launch_bounds__(256) void out_mfma_kernel(
    const ushort* __restrict__ ab, const ushort* __restrict__ WoT,
    const float* __restrict__ bo, float* __restrict__ out) {
  __shared__ ushort As[128 * 64];
  __shared__ ushort Bs[128 * 64];
  const int tid = threadIdx.x;
  const int m0 = blockIdx.x * 128, n0 = blockIdx.y * 128;
  f32x4 acc[4][4];
#pragma unroll
  for (int a = 0; a < 4; ++a)
#pragma unroll
    for (int b = 0; b < 4; ++b) acc[a][b] = (f32x4){0.f, 0.f, 0.f, 0.f};
  gemm_tile(ab, WoT, DINNER, m0, n0, As, Bs, tid, acc);
  const int lane = tid & 63;
  const int w = tid >> 6;
  const int wr = w >> 1, wc = w & 1;
  const int lr = lane & 15, lg = lane >> 4;
#pragma unroll
  for (int mi = 0; mi < 4; ++mi)
#pragma unroll
    for (int ni = 0; ni < 4; ++ni) {
      const int n = n0 + wc * 64 + ni * 16 + lr;
      const float bias = bo[n];
#pragma unroll
      for (int r = 0; r < 4; ++r) {
        const int m = m0 + wr * 64 + mi * 16 + lg * 4 + r;
        out[(size_t)m * DMODEL + n] = acc[mi][ni][r] + bias;
      }
    }
}

// ---------------- Kernel: causal flash attention, bf16 MFMA ----------------
// R8's proven pipeline resized: KVBLK=64, LDS 40KB -> 4 blocks/CU.
// Swapped MFMA (S^T = mfma(K,Q), O^T = mfma(V^T,P)); lane owns q = lane&15.
// Work decode (1280 blocks, longest-first): cid = 79 - (id>>4), bh = id&15.
__global__ __launch_bounds__(256) void attn_mfma_kernel(
    const ushort* __restrict__ qb, const ushort* __restrict__ ksw,
    const ushort* __restrict__ vsw, const float* __restrict__ rpb,
    ushort* __restrict__ ob, float* __restrict__ scratch) {
  __shared__ ushort Ks[2 * 64 * 64];   // dbuf 8KB each: [key 64][d-chunk swz]
  __shared__ ushort Vs[2 * 64 * 64];   // dbuf 8KB each: [d 64][key-chunk swz]
  __shared__ ushort Ps[4 * 16 * 64];   // per-wave P [q 16][key 64] swz, 2KB/wave
  const int tid = threadIdx.x;
  const int lane = tid & 63;
  const int w = tid >> 6;
  const int id = blockIdx.x;
  const int bh = id & 15;
  const int cid = 79 - (id >> 4);   // longest chunks dispatched first
  int qt, ch;
  if (cid < 8)       { qt = cid;                    ch = 0; }
  else if (cid < 24) { qt = 8 + ((cid - 8) >> 1);   ch = (cid - 8) & 1; }
  else if (cid < 48) { qt = 16 + (cid - 24) / 3;    ch = (cid - 24) % 3; }
  else               { qt = 24 + ((cid - 48) >> 2); ch = (cid - 48) & 3; }
  const int t0 = ch * 8;
  const int t1 = min(t0 + 8, qt + 1);
  const int nit = t1 - t0;
  const int partial = (qt >= 8);
  const int bb = bh >> 3, h = bh & 7;
  const int q0 = qt * 64;
  const int lr = lane & 15;
  const int lg = lane >> 4;
  const int qg = q0 + w * 16 + lr;   // this lane's q-row

  const ushort* kbase = ksw + (size_t)bb * 32 * 4096;  // per-b: 32 tiles x 8KB
  const ushort* vbase = vsw + (size_t)bb * 32 * 4096;
  const ushort* ksrcw = kbase + w * 1024 + lane * 8;   // wave's quarter + lane
  const ushort* vsrcw = vbase + w * 1024 + lane * 8;
  ushort* kdstw = Ks + w * 1024;                       // wave-uniform LDS dest
  ushort* vdstw = Vs + w * 1024;

#define ISSUE(tt, bsel)                                                     \
  {                                                                         \
    const ushort* _ks = ksrcw + (size_t)(tt) * 4096;                        \
    const ushort* _vs = vsrcw + (size_t)(tt) * 4096;                        \
    ushort* _kd = kdstw + (bsel) * 4096;                                    \
    ushort* _vd = vdstw + (bsel) * 4096;                                    \
    gld16(_ks, _kd);                                                        \
    gld16(_ks + 512, _kd + 512);                                            \
    gld16(_vs, _vd);                                                        \
    gld16(_vs + 512, _vd + 512);                                            \
  }

  // bias for lane's q-row: 4 x 16B (keys jt*64 + ct*16 + lg*4 .. +3)
#define LOAD_BIAS(tt, dst)                                                  \
  {                                                                         \
    const float* _br = rpb + (size_t)h * NSEQ * NSEQ +                      \
                       (size_t)qg * NSEQ + (tt) * 64 + lg * 4;              \
    _Pragma("unroll")                                                       \
    for (int _ct = 0; _ct < 4; ++_ct)                                       \
      dst[_ct] = *(const f32x4*)(_br + _ct * 16);                           \
  }

  bf16x8 qf[2];
  {
    const ushort* qrow = qb + ((size_t)(bh * NSEQ) + qg) * HD + lg * 8;
    qf[0] = *(const bf16x8*)qrow;
    qf[1] = *(const bf16x8*)(qrow + 32);
  }
  f32x4 oaccT[4];   // O^T: row d = dt*16 + lg*4 + r, col q = lr
#pragma unroll
  for (int dt = 0; dt < 4; ++dt) oaccT[dt] = (f32x4){0.f, 0.f, 0.f, 0.f};
  float m_run = -1e30f, l_run = 0.f;

  f32x4 bias_c[4], bias_n[4];

  // prologue queue: s_0[4], b_0[4], s_1[4]  (tile t0+1 always valid memory)
  ISSUE(t0, 0);
  LOAD_BIAS(t0, bias_c);
  ISSUE(t0 + 1, 1);
  int curb = 0;

  for (int i = 0; i < nit; ++i) {
    const int jt = t0 + i;
    // wait tile i staged; newer in queue: b_i(4) + s_{i+1}(4 if issued)
    if (i < nit - 1) {
      asm volatile("s_waitcnt vmcnt(8)" ::: "memory");
    } else {
      asm volatile("s_waitcnt vmcnt(4)" ::: "memory");
    }
    __builtin_amdgcn_sched_barrier(0);
    __builtin_amdgcn_s_barrier();

    const char* Kc = (const char*)(Ks + curb * 4096);
    const char* Vc = (const char*)(Vs + curb * 4096);
    // ---- S^T = K Q^T : 8 MFMAs over 64 keys
    f32x4 s[4];
    __builtin_amdgcn_s_setprio(1);
#pragma unroll
    for (int ct = 0; ct < 4; ++ct) {
      s[ct] = (f32x4){0.f, 0.f, 0.f, 0.f};
      const int krow = ct * 16 + lr;
#pragma unroll
      for (int kk = 0; kk < 2; ++kk) {
        bf16x8 kf = *(const bf16x8*)(Kc + krow * 128 +
                                     (((kk * 4 + lg) ^ (krow & 7)) << 4));
        s[ct] = __builtin_amdgcn_mfma_f32_16x16x32_bf16(kf, qf[kk], s[ct], 0, 0, 0);
      }
    }
    __builtin_amdgcn_s_setprio(0);
    // ---- prefetch NEXT tile's bias
    if (i + 1 < nit) LOAD_BIAS(jt + 1, bias_n);
    // ---- + bias*log2e, causal mask on the diagonal tile
#pragma unroll
    for (int ct = 0; ct < 4; ++ct)
#pragma unroll
      for (int r = 0; r < 4; ++r)
        s[ct][r] = fmaf(bias_c[ct][r], LOG2E, s[ct][r]);
    if (jt == qt) {
#pragma unroll
      for (int ct = 0; ct < 4; ++ct) {
        const int kg = jt * 64 + ct * 16 + lg * 4;
#pragma unroll
        for (int r = 0; r < 4; ++r)
          if (kg + r > qg) s[ct][r] = -1e30f;
      }
    }
    // ---- online softmax, lane-local row; log2 domain; 2+2 shuffles
    float cm[4];
#pragma unroll
    for (int ct = 0; ct < 4; ++ct)
      cm[ct] = fmaxf(fmaxf(s[ct][0], s[ct][1]), fmaxf(s[ct][2], s[ct][3]));
    float mt = fmaxf(fmaxf(cm[0], cm[1]), fmaxf(cm[2], cm[3]));
    mt = fmaxf(mt, __shfl_xor(mt, 16, 64));
    mt = fmaxf(mt, __shfl_xor(mt, 32, 64));
    const float m_new = fmaxf(m_run, mt);
    const float fac = exp2f(m_run - m_new);
    m_run = m_new;
    float cs[4];
#pragma unroll
    for (int ct = 0; ct < 4; ++ct) {
#pragma unroll
      for (int r = 0; r < 4; ++r) s[ct][r] = exp2f(s[ct][r] - m_new);
      cs[ct] = (s[ct][0] + s[ct][1]) + (s[ct][2] + s[ct][3]);
    }
    float ls = (cs[0] + cs[1]) + (cs[2] + cs[3]);
    ls += __shfl_xor(ls, 16, 64);
    ls += __shfl_xor(ls, 32, 64);
    l_run = l_run * fac + ls;
#pragma unroll
    for (int dt = 0; dt < 4; ++dt) oaccT[dt] *= fac;
    // ---- P -> wave-local LDS [q][key] swz (cvt_pk packs; uint2 stores)
    char* Pw = (char*)Ps + w * 2048;
#pragma unroll
    for (int ct = 0; ct < 4; ++ct) {
      uint u01, u23;
      asm("v_cvt_pk_bf16_f32 %0, %1, %2" : "=v"(u01) : "v"(s[ct][0]), "v"(s[ct][1]));
      asm("v_cvt_pk_bf16_f32 %0, %1, %2" : "=v"(u23) : "v"(s[ct][2]), "v"(s[ct][3]));
      const int chunk = 2 * ct + (lg >> 1);
      uint2 uv; uv.x = u01; uv.y = u23;
      *(uint2*)(Pw + lr * 128 + (((chunk ^ (lr & 7)) << 4) | ((lg & 1) * 8))) = uv;
    }
    // ---- O^T += V^T P : 8 MFMAs
    __builtin_amdgcn_s_setprio(1);
#pragma unroll
    for (int kk = 0; kk < 2; ++kk) {
      bf16x8 pf = *(const bf16x8*)(Pw + lr * 128 +
                                   (((kk * 4 + lg) ^ (lr & 7)) << 4));
#pragma unroll
      for (int dt = 0; dt < 4; ++dt) {
        const int vrow = dt * 16 + lr;
        bf16x8 vf = *(const bf16x8*)(Vc + vrow * 128 +
                                     (((kk * 4 + lg) ^ (vrow & 7)) << 4));
        oaccT[dt] =
            __builtin_amdgcn_mfma_f32_16x16x32_bf16(vf, pf, oaccT[dt], 0, 0, 0);
      }
    }
    __builtin_amdgcn_s_setprio(0);
    __builtin_amdgcn_sched_barrier(0);
    __builtin_amdgcn_s_barrier();  // all waves done reading buf curb
    if (i + 2 < nit) ISSUE(t0 + i + 2, curb);
    if (i + 1 < nit) {
#pragma unroll
      for (int ct = 0; ct < 4; ++ct) bias_c[ct] = bias_n[ct];
    }
    curb ^= 1;
  }
#undef ISSUE
#undef LOAD_BIAS
  if (!partial) {
    // ---- direct epilogue: lane q = lr, d = dt*16 + lg*4 (+0..3)
    const float inv = 1.0f / l_run;
    ushort* dst = ob + ((size_t)(bb * NSEQ) + qg) * DINNER + h * HD;
#pragma unroll
    for (int dt = 0; dt < 4; ++dt) {
      uint u01, u23;
      const float o0 = oaccT[dt][0] * inv, o1 = oaccT[dt][1] * inv;
      const float o2 = oaccT[dt][2] * inv, o3 = oaccT[dt][3] * inv;
      asm("v_cvt_pk_bf16_f32 %0, %1, %2" : "=v"(u01) : "v"(o0), "v"(o1));
      asm("v_cvt_pk_bf16_f32 %0, %1, %2" : "=v"(u23) : "v"(o2), "v"(o3));
      uint2 uv; uv.x = u01; uv.y = u23;
      *(uint2*)(dst + dt * 16 + lg * 4) = uv;
    }
  } else {
    // ---- partial: slot [q 64][d 64] + m[64] + l[64], straight from regs
    float* slot =
        scratch + (size_t)((bh * SLOTS_PER_BH) + slot_off(qt) + ch) * SLOT_F;
    const int row = w * 16 + lr;
#pragma unroll
    for (int dt = 0; dt < 4; ++dt)
      *(f32x4*)(slot + row * 64 + dt * 16 + lg * 4) = oaccT[dt];
    if (lg == 0) {
      slot[4096 + row] = m_run;   // log2-domain
      slot[4160 + row] = l_run;
    }
  }
}

// ---------------- Kernel: merge partials (qt >= 8, 2..4 chunks) ----------
__global__ __launch_bounds__(256) void attn_merge_kernel(
    const float* __restrict__ scratch, ushort* __restrict__ ob) {
  const int bid = blockIdx.x;      // 16 bh x 24 qt
  const int bh = bid / 24;
  const int qt = 8 + bid % 24;
  const int nch = (qt >> 3) + 1;
  const int bb = bh >> 3, h = bh & 7;
  const float* base =
      scratch + (size_t)((bh * SLOTS_PER_BH) + slot_off(qt)) * SLOT_F;
  const int t = threadIdx.x;
  const int r = t >> 2;            // q-row 0..63
  const int c0 = (t & 3) * 16;     // 16 d's
  float ms[4], M = -1e30f;
  for (int s = 0; s < nch; ++s) {
    ms[s] = base[(size_t)s * SLOT_F + 4096 + r];
    M = fmaxf(M, ms[s]);
  }
  float L = 0.f, sc[4];
  for (int s = 0; s < nch; ++s) {
    sc[s] = exp2f(ms[s] - M);
    L += base[(size_t)s * SLOT_F + 4160 + r] * sc[s];
  }
  const float inv = 1.0f / L;
  float o[16];
#pragma unroll
  for (int j = 0; j < 16; ++j) o[j] = 0.f;
  for (int s = 0; s < nch; ++s) {
    const float* orow = base + (size_t)s * SLOT_F + r * 64 + c0;
    const float f = sc[s];
#pragma unroll
    for (int j4 = 0; j4 < 4; ++j4) {
      float4 v = *(const float4*)(orow + j4 * 4);
      o[j4 * 4 + 0] += f * v.x;
      o[j4 * 4 + 1] += f * v.y;
      o[j4 * 4 + 2] += f * v.z;
      o[j4 * 4 + 3] += f * v.w;
    }
  }
  const int qg = qt * 64 + r;
  ushort* dst = ob + ((size_t)(bb * NSEQ) + qg) * DINNER + h * HD + c0;
#pragma unroll
  for (int j = 0; j < 16; ++j) dst[j] = f2bf(o[j] * inv);
}

extern "C" void kernel_launch(void* const* d_in, const int* in_sizes, int n_in,
                              void* d_out, int out_size, void* d_ws, size_t ws_size,
                              hipStream_t stream) {
  (void)in_sizes; (void)n_in; (void)out_size; (void)ws_size;
  const float* x = (const float*)d_in[0];
  const float* rpb = (const float*)d_in[1];
  const float* Wq = (const float*)d_in[2];
  const float* Wkv = (const float*)d_in[3];
  const float* Wo = (const float*)d_in[4];
  const float* bo = (const float*)d_in[5];
  float* out = (float*)d_out;

  ushort* qbb = (ushort*)d_ws;                           // 16*2048*64
  ushort* ksw = qbb + (size_t)NB * NH * NSEQ * HD;       // 2*32 tiles x 8KB
  ushort* vsw = ksw + (size_t)NB * NSEQ * HD;            // 2*32 tiles x 8KB
  ushort* obuf = vsw + (size_t)NB * NSEQ * HD;           // 4096*512 bf16
  ushort* xb = obuf + (size_t)NB * NSEQ * DINNER;        // 4096*1024 bf16
  ushort* WT1 = xb + (size_t)NB * NSEQ * DMODEL;         // 640*1024 bf16
  ushort* WoT = WT1 + (size_t)640 * DMODEL;              // 1024*512 bf16
  float* scratch = (float*)(WoT + (size_t)DMODEL * DINNER);  // 16*72*4224 f32

  cast_x_kernel<<<dim3(2048), 256, 0, stream>>>(x, xb);
  transpose_cast_kernel<<<dim3(16, 10), 256, 0, stream>>>(Wq, Wkv, 512, 128, 512,
                                                          DMODEL, WT1);
  transpose_cast_kernel<<<dim3(8, 16), 256, 0, stream>>>(Wo, Wo, DMODEL, DMODEL,
                                                         DMODEL, DINNER, WoT);
  qkv_mfma_kernel<<<dim3(32, 5), 256, 0, stream>>>(xb, WT1, qbb, ksw, vsw);
  attn_mfma_kernel<<<dim3(1280), 256, 0, stream>>>(qbb, ksw, vsw, rpb, obuf,
                                                   scratch);
  attn_merge_kernel<<<dim3(16 * 24), 256, 0, stream>>>(scratch, obuf);
  out_mfma_kernel<<<dim3(32, 8), 256, 0, stream>>>(obuf, WoT, bo, out);
}

// Round 12
// 82.754 us; speedup vs baseline: 1.9714x; 1.2133x over previous
//
#include <hip/hip_runtime.h>

#define NSEQ 2048
#define NB 2
#define NH 8
#define HD 64
#define DMODEL 1024
#define DINNER 512   // NH*HD

// partial slot for k-split tiles: O[64][64] f32 + m[64] + l[64]
#define SLOT_F 4224
#define LOG2E 1.44269504f

typedef __attribute__((ext_vector_type(8))) short bf16x8;
typedef __attribute__((ext_vector_type(4))) float f32x4;

__device__ __forceinline__ ushort f2bf(float f) {
  uint u = __float_as_uint(f);
  uint r = (u + 0x7fffu + ((u >> 16) & 1u)) >> 16;
  return (ushort)r;
}

// async global->LDS, 16B per lane; LDS dest is wave-uniform base (+lane*16 by HW)
__device__ __forceinline__ void gld16(const ushort* g, ushort* l) {
  __builtin_amdgcn_global_load_lds(
      (const __attribute__((address_space(1))) uint*)g,
      (__attribute__((address_space(3))) uint*)l, 16, 0, 0);
}

// ---------------- prep: BOTH weight transposes in one launch ----------------
// id < 160: WT1[640][1024] <- [Wq | Wkv]   (16 x 10 tiles)
// id >= 160: WoT[1024][512] <- Wo          (8 x 16 tiles)
__global__ __launch_bounds__(256) void transpose_cast_both_kernel(
    const float* __restrict__ Wq, const float* __restrict__ Wkv,
    const float* __restrict__ Wo, ushort* __restrict__ WT1,
    ushort* __restrict__ WoT) {
  __shared__ float t[64][65];
  const int id = blockIdx.x;
  const float *srcA, *srcB;
  int ldA, ldB, nsplit, Ktot, k0, n0;
  ushort* dst;
  if (id < 160) {
    k0 = (id & 15) * 64; n0 = (id >> 4) * 64;
    srcA = Wq; srcB = Wkv; ldA = 512; ldB = 128; nsplit = 512;
    Ktot = 1024; dst = WT1;
  } else {
    const int u = id - 160;
    k0 = (u & 7) * 64; n0 = (u >> 3) * 64;
    srcA = Wo; srcB = Wo; ldA = 1024; ldB = 1024; nsplit = 1024;
    Ktot = 512; dst = WoT;
  }
  const float* src; int ld, nb;
  if (n0 < nsplit) { src = srcA; ld = ldA; nb = n0; }
  else { src = srcB; ld = ldB; nb = n0 - nsplit; }
  const int r = threadIdx.x >> 4;
  const int c = (threadIdx.x & 15) * 4;
#pragma unroll
  for (int rr = r; rr < 64; rr += 16) {
    float4 v = *(const float4*)(src + (size_t)(k0 + rr) * ld + nb + c);
    t[rr][c + 0] = v.x; t[rr][c + 1] = v.y; t[rr][c + 2] = v.z; t[rr][c + 3] = v.w;
  }
  __syncthreads();
#pragma unroll
  for (int rr = r; rr < 64; rr += 16) {
    ushort4 o;
    o.x = f2bf(t[c + 0][rr]); o.y = f2bf(t[c + 1][rr]);
    o.z = f2bf(t[c + 2][rr]); o.w = f2bf(t[c + 3][rr]);
    *(ushort4*)(dst + (size_t)(n0 + rr) * Ktot + k0 + c) = o;
  }
}

// ---------------- GEMM staging helpers (128x64 tile, BK=64) ----------------
// A: 128 rows x 64 k (bf16 source) -> 16KB swizzled
__device__ __forceinline__ void stageA_bf16(const ushort* __restrict__ src, int ld,
                                            int row0, int k0, ushort* lds, int tid) {
#pragma unroll
  for (int i = 0; i < 4; ++i) {
    const int cix = i * 256 + tid;
    const int row = cix >> 3, j = cix & 7;
    uint4 v = *(const uint4*)(src + (size_t)(row0 + row) * ld + k0 + j * 8);
    *(uint4*)((char*)lds + row * 128 + ((j ^ (row & 7)) << 4)) = v;
  }
}
// A: 128 rows x 64 k, FP32 source, cvt_pk->bf16 during stage (fused cast)
__device__ __forceinline__ void stageA_f32(const float* __restrict__ src, int ld,
                                           int row0, int k0, ushort* lds, int tid) {
#pragma unroll
  for (int i = 0; i < 4; ++i) {
    const int cix = i * 256 + tid;
    const int row = cix >> 3, j = cix & 7;
    const float* p = src + (size_t)(row0 + row) * ld + k0 + j * 8;
    float4 a = *(const float4*)p;
    float4 b = *(const float4*)(p + 4);
    uint u0, u1, u2, u3;
    asm("v_cvt_pk_bf16_f32 %0, %1, %2" : "=v"(u0) : "v"(a.x), "v"(a.y));
    asm("v_cvt_pk_bf16_f32 %0, %1, %2" : "=v"(u1) : "v"(a.z), "v"(a.w));
    asm("v_cvt_pk_bf16_f32 %0, %1, %2" : "=v"(u2) : "v"(b.x), "v"(b.y));
    asm("v_cvt_pk_bf16_f32 %0, %1, %2" : "=v"(u3) : "v"(b.z), "v"(b.w));
    uint4 v; v.x = u0; v.y = u1; v.z = u2; v.w = u3;
    *(uint4*)((char*)lds + row * 128 + ((j ^ (row & 7)) << 4)) = v;
  }
}
// B: 64 rows x 64 k (bf16 Bt) -> 8KB swizzled
__device__ __forceinline__ void stageB(const ushort* __restrict__ src, int ld,
                                       int row0, int k0, ushort* lds, int tid) {
#pragma unroll
  for (int i = 0; i < 2; ++i) {
    const int cix = i * 256 + tid;
    const int row = cix >> 3, j = cix & 7;
    uint4 v = *(const uint4*)(src + (size_t)(row0 + row) * ld + k0 + j * 8);
    *(uint4*)((char*)lds + row * 128 + ((j ^ (row & 7)) << 4)) = v;
  }
}

// ---------------- Kernel: QKV GEMM, fused x-cast (bf16 MFMA) ----------------
// 128x64 tile; grid (32, 10). by<8 -> q (scaled); by==8 -> k; by==9 -> v.
// q -> [b*h][n][d]; k,v -> PRE-SWIZZLED LDS-image tiles (R8 attn layouts).
__global__ __launch_bounds__(256) void qkv_mfma_kernel(
    const float* __restrict__ x, const ushort* __restrict__ WT1,
    ushort* __restrict__ qb, ushort* __restrict__ ksw, ushort* __restrict__ vsw) {
  __shared__ ushort As[128 * 64];
  __shared__ ushort Bs[64 * 64];
  const int tid = threadIdx.x;
  const int m0 = blockIdx.x * 128, n0 = blockIdx.y * 64;
  const int lane = tid & 63;
  const int w = tid >> 6;
  const int wr = w >> 1, wc = w & 1;
  const int lr = lane & 15, lg = lane >> 4;
  f32x4 acc[4][2];
#pragma unroll
  for (int a = 0; a < 4; ++a)
#pragma unroll
    for (int b = 0; b < 2; ++b) acc[a][b] = (f32x4){0.f, 0.f, 0.f, 0.f};
  for (int k0 = 0; k0 < DMODEL; k0 += 64) {
    __syncthreads();
    stageA_f32(x, DMODEL, m0, k0, As, tid);
    stageB(WT1, DMODEL, n0, k0, Bs, tid);
    __syncthreads();
#pragma unroll
    for (int kk = 0; kk < 2; ++kk) {
      bf16x8 af[4], bfr[2];
#pragma unroll
      for (int mi = 0; mi < 4; ++mi) {
        const int r = wr * 64 + mi * 16 + lr;
        af[mi] = *(const bf16x8*)((char*)As + r * 128 + (((kk * 4 + lg) ^ (r & 7)) << 4));
      }
#pragma unroll
      for (int ni = 0; ni < 2; ++ni) {
        const int r = wc * 32 + ni * 16 + lr;
        bfr[ni] = *(const bf16x8*)((char*)Bs + r * 128 + (((kk * 4 + lg) ^ (r & 7)) << 4));
      }
#pragma unroll
      for (int mi = 0; mi < 4; ++mi)
#pragma unroll
        for (int ni = 0; ni < 2; ++ni)
          acc[mi][ni] = __builtin_amdgcn_mfma_f32_16x16x32_bf16(af[mi], bfr[ni],
                                                                acc[mi][ni], 0, 0, 0);
    }
  }
#pragma unroll
  for (int mi = 0; mi < 4; ++mi)
#pragma unroll
    for (int ni = 0; ni < 2; ++ni) {
      const int n = n0 + wc * 32 + ni * 16 + lr;
#pragma unroll
      for (int r = 0; r < 4; ++r) {
        const int m = m0 + wr * 64 + mi * 16 + lg * 4 + r;
        const int bb = m >> 11, key = m & (NSEQ - 1);
        const float v = acc[mi][ni][r];
        if (blockIdx.y < 8) {
          const int h = n >> 6, d = n & 63;
          qb[((size_t)((bb * NH + h) * NSEQ) + key) * HD + d] = f2bf(v * 0.125f);
        } else if (blockIdx.y == 8) {
          // K swizzled: tile=key>>6, row=key&63; chunk(d>>3) ^ (row&7)
          const int d = n - DINNER;
          const int t = key >> 6, row = key & 63;
          ksw[(size_t)((bb * 32 + t) * 64 + row) * 64 +
              (((d >> 3) ^ (row & 7)) << 3) + (d & 7)] = f2bf(v);
        } else {
          // V^T swizzled per 128-key pair: row=d; chunk(kk>>3) ^ (d&15)
          const int d = n - DINNER - HD;
          const int pr = key >> 7, kk = key & 127;
          vsw[(size_t)((bb * 16 + pr) * 64 + d) * 128 +
              (((kk >> 3) ^ (d & 15)) << 3) + (kk & 7)] = f2bf(v);
        }
      }
    }
}

// ---------------- Kernel: out GEMM (bf16 MFMA) + bias, fp32 out ------------
// 128x64 tile; grid (32, 16).
__global__ __launch_bounds__(256) void out_mfma_kernel(
    const ushort* __restrict__ ab, const ushort* __restrict__ WoT,
    const float* __restrict__ bo, float* __restrict__ out) {
  __shared__ ushort As[128 * 64];
  __shared__ ushort Bs[64 * 64];
  const int tid = threadIdx.x;
  const int m0 = blockIdx.x * 128, n0 = blockIdx.y * 64;
  const int lane = tid & 63;
  const int w = tid >> 6;
  const int wr = w >> 1, wc = w & 1;
  const int lr = lane & 15, lg = lane >> 4;
  f32x4 acc[4][2];
#pragma unroll
  for (int a = 0; a < 4; ++a)
#pragma unroll
    for (int b = 0; b < 2; ++b) acc[a][b] = (f32x4){0.f, 0.f, 0.f, 0.f};
  for (int k0 = 0; k0 < DINNER; k0 += 64) {
    __syncthreads();
    stageA_bf16(ab, DINNER, m0, k0, As, tid);
    stageB(WoT, DINNER, n0, k0, Bs, tid);
    __syncthreads();
#pragma unroll
    for (int kk = 0; kk < 2; ++kk) {
      bf16x8 af[4], bfr[2];
#pragma unroll
      for (int mi = 0; mi < 4; ++mi) {
        const int r = wr * 64 + mi * 16 + lr;
        af[mi] = *(const bf16x8*)((char*)As + r * 128 + (((kk * 4 + lg) ^ (r & 7)) << 4));
      }
#pragma unroll
      for (int ni = 0; ni < 2; ++ni) {
        const int r = wc * 32 + ni * 16 + lr;
        bfr[ni] = *(const bf16x8*)((char*)Bs + r * 128 + (((kk * 4 + lg) ^ (r & 7)) << 4));
      }
#pragma unroll
      for (int mi = 0; mi < 4; ++mi)
#pragma unroll
        for (int ni = 0; ni < 2; ++ni)
          acc[mi][ni] = __builtin_amdgcn_mfma_f32_16x16x32_bf16(af[mi], bfr[ni],
                                                                acc[mi][ni], 0, 0, 0);
    }
  }
#pragma unroll
  for (int mi = 0; mi < 4; ++mi)
#pragma unroll
    for (int ni = 0; ni < 2; ++ni) {
      const int n = n0 + wc * 32 + ni * 16 + lr;
      const float bias = bo[n];
#pragma unroll
      for (int r = 0; r < 4; ++r) {
        const int m = m0 + wr * 64 + mi * 16 + lg * 4 + r;
        out[(size_t)m * DMODEL + n] = acc[mi][ni][r] + bias;
      }
    }
}

// ---------------- Kernel: causal flash attention (verbatim R8-best) --------
// Work items (768 blocks, longest-first dispatch):
//  id [0,256):   qt=16+(id>>4), chunk 0 (pairs 0..7)  -> partial
//  id [256,512): qt=31-((id-256)>>4), chunk 1 (pairs 8..np-1) -> partial
//  id [512,768): qt=15-((id-512)>>4), whole (pairs 0..np-1)   -> direct
__global__ __launch_bounds__(256) void attn_mfma_kernel(
    const ushort* __restrict__ qb, const ushort* __restrict__ ksw,
    const ushort* __restrict__ vsw, const float* __restrict__ rpb,
    ushort* __restrict__ ob, float* __restrict__ scratch) {
  __shared__ ushort Ks[2 * 128 * 64];   // dbuf: [key 128][d-chunk swz] 16KB each
  __shared__ ushort Vs[2 * 64 * 128];   // dbuf: [d 64][key-chunk swz] 16KB each
  __shared__ ushort Ps[4 * 16 * 128];   // per-wave P [qrow 16][key 128] swz
  const int tid = threadIdx.x;
  const int lane = tid & 63;
  const int w = tid >> 6;
  const int id = blockIdx.x;
  const int bh = id & 15;
  int qt, ch, p0, p1, partial;
  if (id < 256) {
    qt = 16 + (id >> 4); ch = 0; p0 = 0; p1 = 8; partial = 1;
  } else if (id < 512) {
    qt = 31 - ((id - 256) >> 4); ch = 1; p0 = 8; p1 = (qt >> 1) + 1; partial = 1;
  } else {
    qt = 15 - ((id - 512) >> 4); ch = 0; p0 = 0; p1 = (qt >> 1) + 1; partial = 0;
  }
  const int bb = bh >> 3, h = bh & 7;
  const int q0 = qt * 64;
  const int lr = lane & 15;
  const int lg = lane >> 4;
  const int pdiag = qt >> 1;

  const ushort* kpair = ksw + (size_t)bb * 32 * 64 * 64;
  const ushort* vpair = vsw + (size_t)bb * 16 * 64 * 128;
  const ushort* ksrcw = kpair + w * 2048 + lane * 8;
  const ushort* vsrcw = vpair + w * 2048 + lane * 8;
  ushort* kdstw = Ks + w * 2048;
  ushort* vdstw = Vs + w * 2048;

#define ISSUE(pp, bsel)                                                     \
  {                                                                         \
    const ushort* _ks = ksrcw + (size_t)(pp) * 8192;                        \
    const ushort* _vs = vsrcw + (size_t)(pp) * 8192;                        \
    ushort* _kd = kdstw + (bsel) * 8192;                                    \
    ushort* _vd = vdstw + (bsel) * 8192;                                    \
    gld16(_ks + 0 * 512, _kd + 0 * 512);                                    \
    gld16(_ks + 1 * 512, _kd + 1 * 512);                                    \
    gld16(_ks + 2 * 512, _kd + 2 * 512);                                    \
    gld16(_ks + 3 * 512, _kd + 3 * 512);                                    \
    gld16(_vs + 0 * 512, _vd + 0 * 512);                                    \
    gld16(_vs + 1 * 512, _vd + 1 * 512);                                    \
    gld16(_vs + 2 * 512, _vd + 2 * 512);                                    \
    gld16(_vs + 3 * 512, _vd + 3 * 512);                                    \
  }

#define LOAD_BIAS(pp, dst)                                                  \
  {                                                                         \
    const float* _br = rpb + (size_t)h * NSEQ * NSEQ +                      \
                       (size_t)(q0 + w * 16 + lg * 4) * NSEQ +              \
                       (pp) * 128 + lr;                                     \
    _Pragma("unroll")                                                       \
    for (int _ct = 0; _ct < 8; ++_ct)                                       \
      _Pragma("unroll")                                                     \
      for (int _r = 0; _r < 4; ++_r)                                        \
        dst[_ct][_r] = _br[(size_t)_r * NSEQ + _ct * 16];                   \
  }

  bf16x8 qf[2];
  {
    const ushort* qrow =
        qb + ((size_t)(bh * NSEQ) + q0 + w * 16 + lr) * HD + lg * 8;
    qf[0] = *(const bf16x8*)qrow;
    qf[1] = *(const bf16x8*)(qrow + 32);
  }
  f32x4 oacc[4];
  float m_run[4], l_run[4];
#pragma unroll
  for (int r = 0; r < 4; ++r) { m_run[r] = -1e30f; l_run[r] = 0.f; }
#pragma unroll
  for (int dt = 0; dt < 4; ++dt) oacc[dt] = (f32x4){0.f, 0.f, 0.f, 0.f};

  float bias_c[8][4], bias_n[8][4];

  ISSUE(p0, 0);
  LOAD_BIAS(p0, bias_c);
  ISSUE(p0 + 1, 1);
  int curb = 0;

  for (int p = p0; p < p1; ++p) {
    if (p < p1 - 1) {
      asm volatile("s_waitcnt vmcnt(40)" ::: "memory");
    } else {
      asm volatile("s_waitcnt vmcnt(32)" ::: "memory");
    }
    __builtin_amdgcn_sched_barrier(0);
    __builtin_amdgcn_s_barrier();

    const char* Kc = (const char*)(Ks + curb * 8192);
    const char* Vc = (const char*)(Vs + curb * 8192);
    f32x4 s[8];
    __builtin_amdgcn_s_setprio(1);
#pragma unroll
    for (int ct = 0; ct < 8; ++ct) {
      s[ct] = (f32x4){0.f, 0.f, 0.f, 0.f};
      const int krow = ct * 16 + lr;
#pragma unroll
      for (int kk = 0; kk < 2; ++kk) {
        bf16x8 kf = *(const bf16x8*)(Kc + krow * 128 +
                                     (((kk * 4 + lg) ^ (krow & 7)) << 4));
        s[ct] = __builtin_amdgcn_mfma_f32_16x16x32_bf16(qf[kk], kf, s[ct], 0, 0, 0);
      }
    }
    __builtin_amdgcn_s_setprio(0);
    if (p + 1 < p1) LOAD_BIAS(p + 1, bias_n);
#pragma unroll
    for (int ct = 0; ct < 8; ++ct)
#pragma unroll
      for (int r = 0; r < 4; ++r) s[ct][r] += bias_c[ct][r];
    if (p == pdiag) {
      const int qrel = q0 + w * 16 + lg * 4;
#pragma unroll
      for (int ct = 0; ct < 8; ++ct) {
        const int kg = p * 128 + ct * 16 + lr;
#pragma unroll
        for (int r = 0; r < 4; ++r)
          if (kg > qrel + r) s[ct][r] = -1e30f;
      }
    }
    float fac[4];
#pragma unroll
    for (int r = 0; r < 4; ++r) {
      float mt = s[0][r];
#pragma unroll
      for (int ct = 1; ct < 8; ++ct) mt = fmaxf(mt, s[ct][r]);
#pragma unroll
      for (int msk = 1; msk < 16; msk <<= 1)
        mt = fmaxf(mt, __shfl_xor(mt, msk, 64));
      const float m_new = fmaxf(m_run[r], mt);
      fac[r] = __expf(m_run[r] - m_new);
      m_run[r] = m_new;
      float ls = 0.f;
#pragma unroll
      for (int ct = 0; ct < 8; ++ct) {
        const float pv = __expf(s[ct][r] - m_new);
        s[ct][r] = pv;
        ls += pv;
      }
#pragma unroll
      for (int msk = 1; msk < 16; msk <<= 1) ls += __shfl_xor(ls, msk, 64);
      l_run[r] = l_run[r] * fac[r] + ls;
    }
#pragma unroll
    for (int dt = 0; dt < 4; ++dt)
#pragma unroll
      for (int r = 0; r < 4; ++r) oacc[dt][r] *= fac[r];
    char* Pw = (char*)Ps + w * 4096;
#pragma unroll
    for (int ct = 0; ct < 8; ++ct) {
      uint u01, u23;
      asm("v_cvt_pk_bf16_f32 %0, %1, %2" : "=v"(u01) : "v"(s[ct][0]), "v"(s[ct][1]));
      asm("v_cvt_pk_bf16_f32 %0, %1, %2" : "=v"(u23) : "v"(s[ct][2]), "v"(s[ct][3]));
      const int cbyte = (ct * 16 + lr) * 2;
      const int chv = cbyte >> 4, off = cbyte & 15;
      const int r0 = lg * 4;
      *(ushort*)(Pw + (r0 + 0) * 256 + (((chv ^ (r0 + 0)) << 4) | off)) = (ushort)u01;
      *(ushort*)(Pw + (r0 + 1) * 256 + (((chv ^ (r0 + 1)) << 4) | off)) = (ushort)(u01 >> 16);
      *(ushort*)(Pw + (r0 + 2) * 256 + (((chv ^ (r0 + 2)) << 4) | off)) = (ushort)u23;
      *(ushort*)(Pw + (r0 + 3) * 256 + (((chv ^ (r0 + 3)) << 4) | off)) = (ushort)(u23 >> 16);
    }
    __builtin_amdgcn_s_setprio(1);
#pragma unroll
    for (int kk = 0; kk < 4; ++kk) {
      bf16x8 pf = *(const bf16x8*)(Pw + lr * 256 + (((kk * 4 + lg) ^ lr) << 4));
#pragma unroll
      for (int dt = 0; dt < 4; ++dt) {
        const int vrow = dt * 16 + lr;
        bf16x8 vf = *(const bf16x8*)(Vc + vrow * 256 +
                                     (((kk * 4 + lg) ^ (vrow & 15)) << 4));
        oacc[dt] =
            __builtin_amdgcn_mfma_f32_16x16x32_bf16(pf, vf, oacc[dt], 0, 0, 0);
      }
    }
    __builtin_amdgcn_s_setprio(0);
    __builtin_amdgcn_sched_barrier(0);
    __builtin_amdgcn_s_barrier();
    if (p + 2 < p1) ISSUE(p + 2, curb);
    if (p + 1 < p1) {
#pragma unroll
      for (int ct = 0; ct < 8; ++ct)
#pragma unroll
        for (int r = 0; r < 4; ++r) bias_c[ct][r] = bias_n[ct][r];
    }
    curb ^= 1;
  }
#undef ISSUE
#undef LOAD_BIAS
  if (!partial) {
#pragma unroll
    for (int r = 0; r < 4; ++r) {
      const int qg = q0 + w * 16 + lg * 4 + r;
      const float inv = 1.0f / l_run[r];
      ushort* dst = ob + ((size_t)(bb * NSEQ) + qg) * DINNER + h * HD + lr;
#pragma unroll
      for (int dt = 0; dt < 4; ++dt) dst[dt * 16] = f2bf(oacc[dt][r] * inv);
    }
  } else {
    float* slot =
        scratch + (size_t)((bh * 16 + (qt - 16)) * 2 + ch) * SLOT_F;
#pragma unroll
    for (int r = 0; r < 4; ++r) {
      const int row = w * 16 + lg * 4 + r;
#pragma unroll
      for (int dt = 0; dt < 4; ++dt)
        slot[row * 64 + dt * 16 + lr] = oacc[dt][r];
      if (lr == 0) {
        slot[4096 + row] = m_run[r];
        slot[4160 + row] = l_run[r];
      }
    }
  }
}

// ---------------- Kernel: 2-way merge for qt >= 16 ----------------
__global__ __launch_bounds__(256) void attn_merge_kernel(
    const float* __restrict__ scratch, ushort* __restrict__ ob) {
  const int bid = blockIdx.x;        // 16 bh x 16 qt
  const int bh = bid >> 4;
  const int qt = 16 + (bid & 15);
  const int bb = bh >> 3, h = bh & 7;
  const float* s0 = scratch + (size_t)((bh * 16 + (qt - 16)) * 2) * SLOT_F;
  const float* s1 = s0 + SLOT_F;
  const int t = threadIdx.x;
  const int r = t >> 2;
  const int c0 = (t & 3) * 16;
  const float m0 = s0[4096 + r], m1 = s1[4096 + r];
  const float M = fmaxf(m0, m1);
  const float sc0 = __expf(m0 - M), sc1 = __expf(m1 - M);
  const float L = s0[4160 + r] * sc0 + s1[4160 + r] * sc1;
  const float inv = 1.0f / L;
  ushort* dst = ob + ((size_t)(bb * NSEQ) + qt * 64 + r) * DINNER + h * HD + c0;
#pragma unroll
  for (int j4 = 0; j4 < 4; ++j4) {
    float4 a = *(const float4*)(s0 + r * 64 + c0 + j4 * 4);
    float4 b = *(const float4*)(s1 + r * 64 + c0 + j4 * 4);
    dst[j4 * 4 + 0] = f2bf((a.x * sc0 + b.x * sc1) * inv);
    dst[j4 * 4 + 1] = f2bf((a.y * sc0 + b.y * sc1) * inv);
    dst[j4 * 4 + 2] = f2bf((a.z * sc0 + b.z * sc1) * inv);
    dst[j4 * 4 + 3] = f2bf((a.w * sc0 + b.w * sc1) * inv);
  }
}

extern "C" void kernel_launch(void* const* d_in, const int* in_sizes, int n_in,
                              void* d_out, int out_size, void* d_ws, size_t ws_size,
                              hipStream_t stream) {
  (void)in_sizes; (void)n_in; (void)out_size; (void)ws_size;
  const float* x = (const float*)d_in[0];
  const float* rpb = (const float*)d_in[1];
  const float* Wq = (const float*)d_in[2];
  const float* Wkv = (const float*)d_in[3];
  const float* Wo = (const float*)d_in[4];
  const float* bo = (const float*)d_in[5];
  float* out = (float*)d_out;

  ushort* qbb = (ushort*)d_ws;                           // 16*2048*64
  ushort* ksw = qbb + (size_t)NB * NH * NSEQ * HD;       // 2*32 tiles (swz)
  ushort* vsw = ksw + (size_t)NB * NSEQ * HD;            // 2*16 pair-tiles (swz)
  ushort* obuf = vsw + (size_t)NB * NSEQ * HD;           // 4096*512 bf16
  ushort* WT1 = obuf + (size_t)NB * NSEQ * DINNER;       // 640*1024 bf16
  ushort* WoT = WT1 + (size_t)640 * DMODEL;              // 1024*512 bf16
  float* scratch = (float*)(WoT + (size_t)DMODEL * DINNER);  // 512*4224 f32

  transpose_cast_both_kernel<<<dim3(288), 256, 0, stream>>>(Wq, Wkv, Wo, WT1, WoT);
  qkv_mfma_kernel<<<dim3(32, 10), 256, 0, stream>>>(x, WT1, qbb, ksw, vsw);
  attn_mfma_kernel<<<dim3(768), 256, 0, stream>>>(qbb, ksw, vsw, rpb, obuf,
                                                  scratch);
  attn_merge_kernel<<<dim3(256), 256, 0, stream>>>(scratch, obuf);
  out_mfma_kernel<<<dim3(32, 16), 256, 0, stream>>>(obuf, WoT, bo, out);
}